// Round 1
// baseline (308.269 us; speedup 1.0000x reference)
//
#include <hip/hip_runtime.h>
#include <cstdint>

#define S_LEN   2048
#define BATCH   4
#define NCH     4096                    // B*NH*HD channels
#define PLANE   ((size_t)S_LEN * NCH)   // per-gate plane: 8,388,608 elems
#define CHUNK   32
#define NCHUNK  64
#define SN      ((size_t)NCHUNK * NCH)  // 262144 summary slots
#define EPS     1e-8f
#define LDST    280                     // LDS row stride in u16: 560B = 140 dw ≡ 12 (mod 32)

using bf16x8 = __attribute__((ext_vector_type(8))) short;
using f32x4  = __attribute__((ext_vector_type(4))) float;
typedef unsigned short u16;

__device__ __forceinline__ short f2bf(float f) {
  uint32_t u = __builtin_bit_cast(uint32_t, f);
  u += 0x7fffu + ((u >> 16) & 1u);
  return (short)(u >> 16);
}
__device__ __forceinline__ float bf2f(u16 u) {
  return __builtin_bit_cast(float, (uint32_t)u << 16);
}

// ---------------------------------------------------------------------------
// Kernel 1: gate projection. Block = 1024 thr (16 waves) owns one (g,h) and
// 256 rows x all 256 cols (x read ONCE). 32-row tiles (8 iters, half the
// barriers of the 16-row version), 2-slot register prefetch so the staging
// store consumes a load that has been in flight for a full iteration, and
// LDS stride 280 u16 (140 dw = 12 mod 32) for conflict-free ds_read_b128.
// Epilogue fuses tanh(z)->bf16 and sigmoid(o)->bf16; i,f stored fp32.
// ---------------------------------------------------------------------------
__global__ __launch_bounds__(1024) void gates_gemm4(
    const float* __restrict__ x, const float* __restrict__ W,
    const float* __restrict__ bias,
    u16* __restrict__ gz16, float* __restrict__ gi, float* __restrict__ gf,
    u16* __restrict__ go16) {
  __shared__ u16 As[2][32 * LDST];   // 2 x 17,920 B

  const int gh  = blockIdx.x;          // g*4+h
  const int rg  = blockIdx.y;          // 0..31, 256 rows each
  const int g   = gh >> 2, hh = gh & 3;
  const int tid = threadIdx.x;
  const int wave = tid >> 6, lane = tid & 63;
  const int l16 = lane & 15, quad = lane >> 4;
  const int n0  = wave * 16;
  const int row0 = rg * 256;

  // B fragments for this wave's 16-col strip (held all kernel)
  bf16x8 Bf[8];
  {
    const float* wp = W + ((size_t)gh << 16) + (n0 + l16) * 256 + quad * 8;
#pragma unroll
    for (int kt = 0; kt < 8; ++kt) {
      float4 w0 = *(const float4*)(wp + kt * 32);
      float4 w1 = *(const float4*)(wp + kt * 32 + 4);
      bf16x8 b;
      b[0] = f2bf(w0.x); b[1] = f2bf(w0.y); b[2] = f2bf(w0.z); b[3] = f2bf(w0.w);
      b[4] = f2bf(w1.x); b[5] = f2bf(w1.y); b[6] = f2bf(w1.z); b[7] = f2bf(w1.w);
      Bf[kt] = b;
    }
  }
  const float bv = bias[gh * 256 + n0 + l16];

  // staging: thread stages rows sr and sr+16 of the 32-row tile, col4 sc
  const int sr = tid >> 6, sc = tid & 63;
  const float* sbase = x + (size_t)(row0 + sr) * 4096 + g * 1024 + hh * 256 + sc * 4;

  float4 pre[2][2];   // [slot][row half]; slot k&1 holds tile k
  auto gload = [&](int slot, int t) {
    const float* p = sbase + (size_t)t * 32 * 4096;
    pre[slot][0] = *(const float4*)p;
    pre[slot][1] = *(const float4*)(p + 16 * 4096);
  };
  auto swrite = [&](int slot, int buf) {
#pragma unroll
    for (int rh = 0; rh < 2; ++rh) {
      float4 v = pre[slot][rh];
      ushort4 u;
      u.x = (u16)f2bf(v.x); u.y = (u16)f2bf(v.y);
      u.z = (u16)f2bf(v.z); u.w = (u16)f2bf(v.w);
      *(ushort4*)&As[buf][(sr + rh * 16) * LDST + sc * 4] = u;
    }
  };

  gload(0, 0);
  gload(1, 1);
  swrite(0, 0);            // waits only on tile-0 loads (counted vmcnt)
  __syncthreads();

  for (int t = 0; t < 8; ++t) {
    if (t + 2 < 8) gload(t & 1, t + 2);          // slot t&1 was consumed at iter t-1
    if (t + 1 < 8) swrite((t + 1) & 1, (t + 1) & 1);  // load issued a full iter ago

    f32x4 acc0 = (f32x4){0.f, 0.f, 0.f, 0.f};
    f32x4 acc1 = (f32x4){0.f, 0.f, 0.f, 0.f};
#pragma unroll
    for (int kt = 0; kt < 8; ++kt) {
      bf16x8 a0 = *(const bf16x8*)&As[t & 1][l16 * LDST + kt * 32 + quad * 8];
      bf16x8 a1 = *(const bf16x8*)&As[t & 1][(l16 + 16) * LDST + kt * 32 + quad * 8];
      acc0 = __builtin_amdgcn_mfma_f32_16x16x32_bf16(a0, Bf[kt], acc0, 0, 0, 0);
      acc1 = __builtin_amdgcn_mfma_f32_16x16x32_bf16(a1, Bf[kt], acc1, 0, 0, 0);
    }

    // epilogue (fire-and-forget stores, overlap with in-flight staging)
#pragma unroll
    for (int rt = 0; rt < 2; ++rt) {
#pragma unroll
      for (int rr = 0; rr < 4; ++rr) {
        int rowi = row0 + t * 32 + rt * 16 + quad * 4 + rr;
        int sx = rowi & (S_LEN - 1);
        int bx = rowi >> 11;
        size_t idx = (size_t)sx * NCH + bx * 1024 + hh * 256 + n0 + l16;
        float v = (rt ? acc1[rr] : acc0[rr]) + bv;
        if (g == 1)      gi[idx] = v;
        else if (g == 2) gf[idx] = v;
        else if (g == 0) {
          float tz = 1.f - 2.f * __builtin_amdgcn_rcpf(1.f + __expf(2.f * v));
          gz16[idx] = (u16)f2bf(tz);
        } else {
          float s = __builtin_amdgcn_rcpf(1.f + __expf(-v));
          go16[idx] = (u16)f2bf(s);
        }
      }
    }
    __syncthreads();
  }
}

// ---------------------------------------------------------------------------
// Kernel 2: pass 1 — per (channel, 32-step chunk) locally-stabilized
// summaries: A = sum(f); B = stabilizer max-scan from -inf; D/Dn = c/n with
// zero entering state. 262144 threads. (unchanged)
// ---------------------------------------------------------------------------
__global__ __launch_bounds__(256) void scan_pass1(
    const u16* __restrict__ gz16, const float* __restrict__ gi,
    const float* __restrict__ gf, float* __restrict__ sums) {
  const int t  = blockIdx.x * 256 + threadIdx.x;   // 262144
  const int ch = t & (NCH - 1);
  const int ck = t >> 12;                           // 0..63
  const size_t base = (size_t)ck * CHUNK * NCH + ch;

  float A = 0.f, Bv = -1e30f, D = 0.f, Dn = 0.f;

  float z0[8], i0[8], f0[8], z1[8], i1[8], f1[8];
#pragma unroll
  for (int j = 0; j < 8; ++j) {
    size_t off = base + (size_t)j * NCH;
    z0[j] = bf2f(gz16[off]); i0[j] = gi[off]; f0[j] = gf[off];
  }

  auto step = [&](float z, float i, float f) {
    float Bn = fmaxf(Bv + f, i);
    float e1 = __expf(Bv + f - Bn);
    float e2 = __expf(i - Bn);
    D  = e1 * D + e2 * z;
    Dn = e1 * Dn + e2;
    A += f;
    Bv = Bn;
  };

  for (int gb = 0; gb < 4; gb += 2) {
#pragma unroll
    for (int j = 0; j < 8; ++j) {
      size_t off = base + (size_t)((gb + 1) * 8 + j) * NCH;
      z1[j] = bf2f(gz16[off]); i1[j] = gi[off]; f1[j] = gf[off];
    }
#pragma unroll
    for (int j = 0; j < 8; ++j) step(z0[j], i0[j], f0[j]);
    if (gb + 2 < 4) {
#pragma unroll
      for (int j = 0; j < 8; ++j) {
        size_t off = base + (size_t)((gb + 2) * 8 + j) * NCH;
        z0[j] = bf2f(gz16[off]); i0[j] = gi[off]; f0[j] = gf[off];
      }
    }
#pragma unroll
    for (int j = 0; j < 8; ++j) step(z1[j], i1[j], f1[j]);
  }

  const size_t idx = (size_t)ck * NCH + ch;
  sums[idx]          = A;
  sums[SN + idx]     = Bv;
  sums[2 * SN + idx] = D;
  sums[3 * SN + idx] = Dn;
}

// ---------------------------------------------------------------------------
// Kernel 3: pass 2 — wave-parallel scan. One 64-lane wave per channel,
// lane = chunk. The chunk transform (A,B,D,N) is associative under
//   combine(early,late): A=Ae+Al; B=max(Be+Al, Bl);
//                        D=e^(Be+Al-B)De + e^(Bl-B)Dl; same for N.
// Hillis-Steele inclusive scan (6 shfl_up rounds), shift by 1 for the
// exclusive prefix, apply to zero entering state. 4096 waves (full device)
// replaces 16-block / 64-serial-iteration latency chain.
// ---------------------------------------------------------------------------
__global__ __launch_bounds__(256) void scan_pass2(
    const float* __restrict__ sums, float* __restrict__ ent) {
  const int gt   = blockIdx.x * 256 + threadIdx.x;   // 262144 threads
  const int ch   = gt >> 6;                          // 0..4095, one wave per ch
  const int lane = gt & 63;                          // chunk index

  const size_t idx = (size_t)lane * NCH + ch;
  float A = sums[idx];
  float B = sums[SN + idx];
  float D = sums[2 * SN + idx];
  float N = sums[3 * SN + idx];

#pragma unroll
  for (int d = 1; d < 64; d <<= 1) {
    float A1 = __shfl_up(A, d, 64);
    float B1 = __shfl_up(B, d, 64);
    float D1 = __shfl_up(D, d, 64);
    float N1 = __shfl_up(N, d, 64);
    if (lane >= d) {
      float Bn = fmaxf(B1 + A, B);
      float e1 = __expf(B1 + A - Bn);
      float e2 = __expf(B - Bn);
      D = e1 * D1 + e2 * D;
      N = e1 * N1 + e2 * N;
      A = A + A1;
      B = Bn;
    }
  }

  // exclusive prefix = inclusive of lane-1; lane 0 = identity
  float Ae = __shfl_up(A, 1, 64);
  float Be = __shfl_up(B, 1, 64);
  float De = __shfl_up(D, 1, 64);
  float Ne = __shfl_up(N, 1, 64);

  float c, n, m;
  if (lane == 0) {
    c = 0.f; n = 0.f; m = 0.f;
  } else {
    m = fmaxf(Ae, Be);           // transform applied to (c,n,m)=(0,0,0)
    float eb = __expf(Be - m);
    c = eb * De;
    n = eb * Ne;
  }

  ent[idx]          = c;
  ent[SN + idx]     = n;
  ent[2 * SN + idx] = m;
}

// ---------------------------------------------------------------------------
// Kernel 4: pass 3 — read entering state, replay 32 steps of the original
// recurrence, write h. Last chunk writes finals. 262144 threads. (unchanged)
// ---------------------------------------------------------------------------
__global__ __launch_bounds__(256) void scan_pass3(
    const u16* __restrict__ gz16, const float* __restrict__ gi,
    const float* __restrict__ gf, const u16* __restrict__ go16,
    const float* __restrict__ ent, float* __restrict__ out) {
  const int t  = blockIdx.x * 256 + threadIdx.x;
  const int ch = t & (NCH - 1);
  const int ck = t >> 12;

  const size_t idx0 = (size_t)ck * NCH + ch;
  float c = ent[idx0];
  float n = ent[SN + idx0];
  float m = ent[2 * SN + idx0];

  const int b = ch >> 10, d = ch & 1023;
  const size_t base = (size_t)ck * CHUNK * NCH + ch;
  float* hout = out + (size_t)b * (S_LEN * 1024) + (size_t)(ck * CHUNK) * 1024 + d;

  float hv = 0.f;
  float z0[8], i0[8], f0[8], o0[8], z1[8], i1[8], f1[8], o1[8];
#pragma unroll
  for (int j = 0; j < 8; ++j) {
    size_t off = base + (size_t)j * NCH;
    z0[j] = bf2f(gz16[off]); i0[j] = gi[off]; f0[j] = gf[off]; o0[j] = bf2f(go16[off]);
  }

  auto step = [&](float z, float i, float f, float o, int s) {
    float mn = fmaxf(f + m, i);
    float fh = __expf(f + m - mn);
    float ih = __expf(i - mn);
    c = fh * c + ih * z;
    n = fh * n + ih;
    m = mn;
    hv = o * c * __builtin_amdgcn_rcpf(n + EPS);
    hout[(size_t)s * 1024] = hv;
  };

  for (int gb = 0; gb < 4; gb += 2) {
#pragma unroll
    for (int j = 0; j < 8; ++j) {
      size_t off = base + (size_t)((gb + 1) * 8 + j) * NCH;
      z1[j] = bf2f(gz16[off]); i1[j] = gi[off]; f1[j] = gf[off]; o1[j] = bf2f(go16[off]);
    }
#pragma unroll
    for (int j = 0; j < 8; ++j) step(z0[j], i0[j], f0[j], o0[j], gb * 8 + j);
    if (gb + 2 < 4) {
#pragma unroll
      for (int j = 0; j < 8; ++j) {
        size_t off = base + (size_t)((gb + 2) * 8 + j) * NCH;
        z0[j] = bf2f(gz16[off]); i0[j] = gi[off]; f0[j] = gf[off]; o0[j] = bf2f(go16[off]);
      }
    }
#pragma unroll
    for (int j = 0; j < 8; ++j) step(z1[j], i1[j], f1[j], o1[j], (gb + 1) * 8 + j);
  }

  if (ck == NCHUNK - 1) {
    float* fin = out + (size_t)BATCH * S_LEN * 1024;   // 8,388,608
    fin[ch]            = hv;
    fin[NCH + ch]      = c;
    fin[2 * NCH + ch]  = n;
    fin[3 * NCH + ch]  = m;
  }
}

extern "C" void kernel_launch(void* const* d_in, const int* in_sizes, int n_in,
                              void* d_out, int out_size, void* d_ws, size_t ws_size,
                              hipStream_t stream) {
  const float* x    = (const float*)d_in[0];   // [4,2048,4096] fp32
  const float* W    = (const float*)d_in[1];   // [4,4,256,256] fp32
  const float* bias = (const float*)d_in[2];   // [4,4,256] fp32
  float* out = (float*)d_out;

  // ws layout: z bf16 | i fp32 | f fp32 | o bf16 | sums 4*SN | ent 3*SN
  u16*   gz16 = (u16*)d_ws;                       // 16.78 MB
  float* gi   = (float*)(gz16 + PLANE);           // 33.55 MB
  float* gf   = gi + PLANE;                       // 33.55 MB
  u16*   go16 = (u16*)(gf + PLANE);               // 16.78 MB
  float* sums = (float*)(go16 + PLANE);           // 4.19 MB
  float* ent  = sums + 4 * SN;                    // 3.15 MB  (total ~108 MB)

  gates_gemm4<<<dim3(16, 32), dim3(1024), 0, stream>>>(x, W, bias, gz16, gi, gf, go16);
  scan_pass1<<<dim3(1024), dim3(256), 0, stream>>>(gz16, gi, gf, sums);
  scan_pass2<<<dim3(1024), dim3(256), 0, stream>>>(sums, ent);
  scan_pass3<<<dim3(1024), dim3(256), 0, stream>>>(gz16, gi, gf, go16, ent, out);
}

// Round 2
// 285.390 us; speedup vs baseline: 1.0802x; 1.0802x over previous
//
#include <hip/hip_runtime.h>
#include <cstdint>

#define S_LEN   2048
#define BATCH   4
#define NCH     4096                    // B*NH*HD channels
#define PLANE   ((size_t)S_LEN * NCH)   // per-gate plane: 8,388,608 elems
#define CHUNK   32
#define NCHUNK  64
#define SN      ((size_t)NCHUNK * NCH)  // 262144 summary slots
#define EPS     1e-8f
#define LDST    264                     // LDS row stride in u16 (b128 reads are bank-optimal; stride irrelevant)

using bf16x8 = __attribute__((ext_vector_type(8))) short;
using f32x4  = __attribute__((ext_vector_type(4))) float;
typedef unsigned short u16;

__device__ __forceinline__ short f2bf(float f) {
  uint32_t u = __builtin_bit_cast(uint32_t, f);
  u += 0x7fffu + ((u >> 16) & 1u);
  return (short)(u >> 16);
}
__device__ __forceinline__ float bf2f(u16 u) {
  return __builtin_bit_cast(float, (uint32_t)u << 16);
}

// ---------------------------------------------------------------------------
// Kernel 1: gate projection. Block = 1024 thr (16 waves) owns one (g,h) and
// 256 rows x 256 cols (x read ONCE). Tri-buffered LDS (3 x 16-row tiles) +
// 2-tile-deep register prefetch in NAMED registers preA/preB (explicit
// even/odd pair loop — no runtime-indexed register arrays, rule #20).
// Per iteration: issue load for t+2, LDS-write tile t+1 (its load has been
// in flight a full iteration), compute tile t, barrier. The swrite's vmcnt
// wait is therefore ~free. Epilogue fuses tanh(z)/sigmoid(o) -> bf16.
// ---------------------------------------------------------------------------
__global__ __launch_bounds__(1024) void gates_gemm5(
    const float* __restrict__ x, const float* __restrict__ W,
    const float* __restrict__ bias,
    u16* __restrict__ gz16, float* __restrict__ gi, float* __restrict__ gf,
    u16* __restrict__ go16) {
  __shared__ u16 As[3][16 * LDST];   // 3 x 8448 B = 25,344 B

  const int gh  = blockIdx.x;          // g*4+h
  const int rg  = blockIdx.y;          // 0..31, 256 rows each
  const int g   = gh >> 2, hh = gh & 3;
  const int tid = threadIdx.x;
  const int wave = tid >> 6, lane = tid & 63;
  const int l16 = lane & 15, quad = lane >> 4;
  const int n0  = wave * 16;
  const int row0 = rg * 256;

  // B fragments for this wave's 16-col strip (held all kernel)
  bf16x8 Bf[8];
  {
    const float* wp = W + ((size_t)gh << 16) + (n0 + l16) * 256 + quad * 8;
#pragma unroll
    for (int kt = 0; kt < 8; ++kt) {
      float4 w0 = *(const float4*)(wp + kt * 32);
      float4 w1 = *(const float4*)(wp + kt * 32 + 4);
      bf16x8 b;
      b[0] = f2bf(w0.x); b[1] = f2bf(w0.y); b[2] = f2bf(w0.z); b[3] = f2bf(w0.w);
      b[4] = f2bf(w1.x); b[5] = f2bf(w1.y); b[6] = f2bf(w1.z); b[7] = f2bf(w1.w);
      Bf[kt] = b;
    }
  }
  const float bv = bias[gh * 256 + n0 + l16];

  // staging: thread loads float4 #tid of the tile (row = tid>>6, col4 = tid&63)
  const int sr = tid >> 6, sc = tid & 63;
  const float* sbase = x + (size_t)(row0 + sr) * 4096 + g * 1024 + hh * 256 + sc * 4;

  float4 preA, preB;   // named 2-deep prefetch slots (even/odd tiles)
  auto gloadA = [&](int t) { preA = *(const float4*)(sbase + (size_t)t * 16 * 4096); };
  auto gloadB = [&](int t) { preB = *(const float4*)(sbase + (size_t)t * 16 * 4096); };
  auto swriteA = [&](int buf) {
    ushort4 u;
    u.x = (u16)f2bf(preA.x); u.y = (u16)f2bf(preA.y);
    u.z = (u16)f2bf(preA.z); u.w = (u16)f2bf(preA.w);
    *(ushort4*)&As[buf][sr * LDST + sc * 4] = u;
  };
  auto swriteB = [&](int buf) {
    ushort4 u;
    u.x = (u16)f2bf(preB.x); u.y = (u16)f2bf(preB.y);
    u.z = (u16)f2bf(preB.z); u.w = (u16)f2bf(preB.w);
    *(ushort4*)&As[buf][sr * LDST + sc * 4] = u;
  };

  auto compute = [&](int buf, int t) {
    f32x4 acc = (f32x4){0.f, 0.f, 0.f, 0.f};
#pragma unroll
    for (int kt = 0; kt < 8; ++kt) {
      bf16x8 a = *(const bf16x8*)&As[buf][l16 * LDST + kt * 32 + quad * 8];
      acc = __builtin_amdgcn_mfma_f32_16x16x32_bf16(a, Bf[kt], acc, 0, 0, 0);
    }
    // epilogue (fire-and-forget stores)
#pragma unroll
    for (int rr = 0; rr < 4; ++rr) {
      int rowi = row0 + t * 16 + quad * 4 + rr;
      int sx = rowi & (S_LEN - 1);
      int bx = rowi >> 11;
      size_t idx = (size_t)sx * NCH + bx * 1024 + hh * 256 + n0 + l16;
      float v = acc[rr] + bv;
      if (g == 1)      gi[idx] = v;
      else if (g == 2) gf[idx] = v;
      else if (g == 0) {
        float tz = 1.f - 2.f * __builtin_amdgcn_rcpf(1.f + __expf(2.f * v));
        gz16[idx] = (u16)f2bf(tz);
      } else {
        float s = __builtin_amdgcn_rcpf(1.f + __expf(-v));
        go16[idx] = (u16)f2bf(s);
      }
    }
  };

  // prologue: tiles 0,1 loaded; tile 0 staged to buf0
  gloadA(0);
  gloadB(1);
  swriteA(0);
  __syncthreads();

  int bT = 0;   // buf holding tile tt at pair top
  for (int tt = 0; tt < 16; tt += 2) {
    int b1 = bT + 1; if (b1 >= 3) b1 -= 3;
    int b2 = b1 + 1; if (b2 >= 3) b2 -= 3;

    // t = tt (even): preB holds tile tt+1 (loaded one iteration ago)
    if (tt + 2 < 16) gloadA(tt + 2);
    swriteB(b1);                        // tile tt+1 -> buf b1
    compute(bT, tt);
    __syncthreads();

    // t = tt+1 (odd): preA holds tile tt+2 (loaded one iteration ago)
    if (tt + 3 < 16) gloadB(tt + 3);
    if (tt + 2 < 16) swriteA(b2);       // tile tt+2 -> buf b2
    compute(b1, tt + 1);
    __syncthreads();

    bT = b2;
  }
}

// ---------------------------------------------------------------------------
// Kernel 2: pass 1 — per (channel, 32-step chunk) locally-stabilized
// summaries: A = sum(f); B = stabilizer max-scan from -inf; D/Dn = c/n with
// zero entering state. 262144 threads. (unchanged)
// ---------------------------------------------------------------------------
__global__ __launch_bounds__(256) void scan_pass1(
    const u16* __restrict__ gz16, const float* __restrict__ gi,
    const float* __restrict__ gf, float* __restrict__ sums) {
  const int t  = blockIdx.x * 256 + threadIdx.x;   // 262144
  const int ch = t & (NCH - 1);
  const int ck = t >> 12;                           // 0..63
  const size_t base = (size_t)ck * CHUNK * NCH + ch;

  float A = 0.f, Bv = -1e30f, D = 0.f, Dn = 0.f;

  float z0[8], i0[8], f0[8], z1[8], i1[8], f1[8];
#pragma unroll
  for (int j = 0; j < 8; ++j) {
    size_t off = base + (size_t)j * NCH;
    z0[j] = bf2f(gz16[off]); i0[j] = gi[off]; f0[j] = gf[off];
  }

  auto step = [&](float z, float i, float f) {
    float Bn = fmaxf(Bv + f, i);
    float e1 = __expf(Bv + f - Bn);
    float e2 = __expf(i - Bn);
    D  = e1 * D + e2 * z;
    Dn = e1 * Dn + e2;
    A += f;
    Bv = Bn;
  };

  for (int gb = 0; gb < 4; gb += 2) {
#pragma unroll
    for (int j = 0; j < 8; ++j) {
      size_t off = base + (size_t)((gb + 1) * 8 + j) * NCH;
      z1[j] = bf2f(gz16[off]); i1[j] = gi[off]; f1[j] = gf[off];
    }
#pragma unroll
    for (int j = 0; j < 8; ++j) step(z0[j], i0[j], f0[j]);
    if (gb + 2 < 4) {
#pragma unroll
      for (int j = 0; j < 8; ++j) {
        size_t off = base + (size_t)((gb + 2) * 8 + j) * NCH;
        z0[j] = bf2f(gz16[off]); i0[j] = gi[off]; f0[j] = gf[off];
      }
    }
#pragma unroll
    for (int j = 0; j < 8; ++j) step(z1[j], i1[j], f1[j]);
  }

  const size_t idx = (size_t)ck * NCH + ch;
  sums[idx]          = A;
  sums[SN + idx]     = Bv;
  sums[2 * SN + idx] = D;
  sums[3 * SN + idx] = Dn;
}

// ---------------------------------------------------------------------------
// Kernel 3: pass 2 — wave-parallel scan. One 64-lane wave per channel,
// lane = chunk. Hillis-Steele inclusive scan (6 shfl_up rounds), shift by 1
// for the exclusive prefix, apply to zero entering state. (unchanged)
// ---------------------------------------------------------------------------
__global__ __launch_bounds__(256) void scan_pass2(
    const float* __restrict__ sums, float* __restrict__ ent) {
  const int gt   = blockIdx.x * 256 + threadIdx.x;   // 262144 threads
  const int ch   = gt >> 6;                          // 0..4095, one wave per ch
  const int lane = gt & 63;                          // chunk index

  const size_t idx = (size_t)lane * NCH + ch;
  float A = sums[idx];
  float B = sums[SN + idx];
  float D = sums[2 * SN + idx];
  float N = sums[3 * SN + idx];

#pragma unroll
  for (int d = 1; d < 64; d <<= 1) {
    float A1 = __shfl_up(A, d, 64);
    float B1 = __shfl_up(B, d, 64);
    float D1 = __shfl_up(D, d, 64);
    float N1 = __shfl_up(N, d, 64);
    if (lane >= d) {
      float Bn = fmaxf(B1 + A, B);
      float e1 = __expf(B1 + A - Bn);
      float e2 = __expf(B - Bn);
      D = e1 * D1 + e2 * D;
      N = e1 * N1 + e2 * N;
      A = A + A1;
      B = Bn;
    }
  }

  // exclusive prefix = inclusive of lane-1; lane 0 = identity
  float Ae = __shfl_up(A, 1, 64);
  float Be = __shfl_up(B, 1, 64);
  float De = __shfl_up(D, 1, 64);
  float Ne = __shfl_up(N, 1, 64);

  float c, n, m;
  if (lane == 0) {
    c = 0.f; n = 0.f; m = 0.f;
  } else {
    m = fmaxf(Ae, Be);           // transform applied to (c,n,m)=(0,0,0)
    float eb = __expf(Be - m);
    c = eb * De;
    n = eb * Ne;
  }

  ent[idx]          = c;
  ent[SN + idx]     = n;
  ent[2 * SN + idx] = m;
}

// ---------------------------------------------------------------------------
// Kernel 4: pass 3 — read entering state, replay 32 steps of the original
// recurrence, write h. Last chunk writes finals. 262144 threads. (unchanged)
// ---------------------------------------------------------------------------
__global__ __launch_bounds__(256) void scan_pass3(
    const u16* __restrict__ gz16, const float* __restrict__ gi,
    const float* __restrict__ gf, const u16* __restrict__ go16,
    const float* __restrict__ ent, float* __restrict__ out) {
  const int t  = blockIdx.x * 256 + threadIdx.x;
  const int ch = t & (NCH - 1);
  const int ck = t >> 12;

  const size_t idx0 = (size_t)ck * NCH + ch;
  float c = ent[idx0];
  float n = ent[SN + idx0];
  float m = ent[2 * SN + idx0];

  const int b = ch >> 10, d = ch & 1023;
  const size_t base = (size_t)ck * CHUNK * NCH + ch;
  float* hout = out + (size_t)b * (S_LEN * 1024) + (size_t)(ck * CHUNK) * 1024 + d;

  float hv = 0.f;
  float z0[8], i0[8], f0[8], o0[8], z1[8], i1[8], f1[8], o1[8];
#pragma unroll
  for (int j = 0; j < 8; ++j) {
    size_t off = base + (size_t)j * NCH;
    z0[j] = bf2f(gz16[off]); i0[j] = gi[off]; f0[j] = gf[off]; o0[j] = bf2f(go16[off]);
  }

  auto step = [&](float z, float i, float f, float o, int s) {
    float mn = fmaxf(f + m, i);
    float fh = __expf(f + m - mn);
    float ih = __expf(i - mn);
    c = fh * c + ih * z;
    n = fh * n + ih;
    m = mn;
    hv = o * c * __builtin_amdgcn_rcpf(n + EPS);
    hout[(size_t)s * 1024] = hv;
  };

  for (int gb = 0; gb < 4; gb += 2) {
#pragma unroll
    for (int j = 0; j < 8; ++j) {
      size_t off = base + (size_t)((gb + 1) * 8 + j) * NCH;
      z1[j] = bf2f(gz16[off]); i1[j] = gi[off]; f1[j] = gf[off]; o1[j] = bf2f(go16[off]);
    }
#pragma unroll
    for (int j = 0; j < 8; ++j) step(z0[j], i0[j], f0[j], o0[j], gb * 8 + j);
    if (gb + 2 < 4) {
#pragma unroll
      for (int j = 0; j < 8; ++j) {
        size_t off = base + (size_t)((gb + 2) * 8 + j) * NCH;
        z0[j] = bf2f(gz16[off]); i0[j] = gi[off]; f0[j] = gf[off]; o0[j] = bf2f(go16[off]);
      }
    }
#pragma unroll
    for (int j = 0; j < 8; ++j) step(z1[j], i1[j], f1[j], o1[j], (gb + 1) * 8 + j);
  }

  if (ck == NCHUNK - 1) {
    float* fin = out + (size_t)BATCH * S_LEN * 1024;   // 8,388,608
    fin[ch]            = hv;
    fin[NCH + ch]      = c;
    fin[2 * NCH + ch]  = n;
    fin[3 * NCH + ch]  = m;
  }
}

extern "C" void kernel_launch(void* const* d_in, const int* in_sizes, int n_in,
                              void* d_out, int out_size, void* d_ws, size_t ws_size,
                              hipStream_t stream) {
  const float* x    = (const float*)d_in[0];   // [4,2048,4096] fp32
  const float* W    = (const float*)d_in[1];   // [4,4,256,256] fp32
  const float* bias = (const float*)d_in[2];   // [4,4,256] fp32
  float* out = (float*)d_out;

  // ws layout: z bf16 | i fp32 | f fp32 | o bf16 | sums 4*SN | ent 3*SN
  u16*   gz16 = (u16*)d_ws;                       // 16.78 MB
  float* gi   = (float*)(gz16 + PLANE);           // 33.55 MB
  float* gf   = gi + PLANE;                       // 33.55 MB
  u16*   go16 = (u16*)(gf + PLANE);               // 16.78 MB
  float* sums = (float*)(go16 + PLANE);           // 4.19 MB
  float* ent  = sums + 4 * SN;                    // 3.15 MB  (total ~108 MB)

  gates_gemm5<<<dim3(16, 32), dim3(1024), 0, stream>>>(x, W, bias, gz16, gi, gf, go16);
  scan_pass1<<<dim3(1024), dim3(256), 0, stream>>>(gz16, gi, gf, sums);
  scan_pass2<<<dim3(1024), dim3(256), 0, stream>>>(sums, ent);
  scan_pass3<<<dim3(1024), dim3(256), 0, stream>>>(gz16, gi, gf, go16, ent, out);
}

// Round 3
// 278.400 us; speedup vs baseline: 1.1073x; 1.0251x over previous
//
#include <hip/hip_runtime.h>
#include <cstdint>

#define S_LEN   2048
#define BATCH   4
#define NCH     4096                    // B*NH*HD channels
#define PLANE   ((size_t)S_LEN * NCH)   // per-gate plane: 8,388,608 elems
#define CHUNK   16
#define NCHUNK  128
#define SN      ((size_t)NCHUNK * NCH)  // 524288 summary slots
#define EPS     1e-8f

using bf16x8 = __attribute__((ext_vector_type(8))) short;
using f32x4  = __attribute__((ext_vector_type(4))) float;
typedef unsigned short u16;

__device__ __forceinline__ short f2bf(float f) {
  uint32_t u = __builtin_bit_cast(uint32_t, f);
  u += 0x7fffu + ((u >> 16) & 1u);
  return (short)(u >> 16);
}
__device__ __forceinline__ float bf2f(u16 u) {
  return __builtin_bit_cast(float, (uint32_t)u << 16);
}
__device__ __forceinline__ u16 f2h(float f) {
  _Float16 h = (_Float16)f;
  return __builtin_bit_cast(unsigned short, h);
}
__device__ __forceinline__ float h2f(u16 u) {
  return (float)__builtin_bit_cast(_Float16, u);
}

// ---------------------------------------------------------------------------
// Kernel 1: gate projection — EXACT round-0 structure (88 us, the best
// measured), only change: i and f stored as fp16 (u16) instead of fp32.
// Block = 1024 thr (16 waves) owns one (g,h) and 256 rows x 256 cols.
// Double-buffered LDS bf16 tile (16x264); wave w holds B for its 16-col
// strip; one barrier per 16-row tile. Epilogue fuses tanh(z)/sigmoid(o).
// ---------------------------------------------------------------------------
__global__ __launch_bounds__(1024) void gates_gemm6(
    const float* __restrict__ x, const float* __restrict__ W,
    const float* __restrict__ bias,
    u16* __restrict__ gz16, u16* __restrict__ gi16, u16* __restrict__ gf16,
    u16* __restrict__ go16) {
  __shared__ u16 As[2][16 * 264];   // 2 x 8448 B

  const int gh  = blockIdx.x;          // g*4+h
  const int rg  = blockIdx.y;          // 0..31, 256 rows each
  const int g   = gh >> 2, hh = gh & 3;
  const int tid = threadIdx.x;
  const int wave = tid >> 6, lane = tid & 63;
  const int l16 = lane & 15, quad = lane >> 4;
  const int n0  = wave * 16;
  const int row0 = rg * 256;

  // B fragments for this wave's 16-col strip (held all kernel)
  bf16x8 Bf[8];
  {
    const float* wp = W + ((size_t)gh << 16) + (n0 + l16) * 256 + quad * 8;
#pragma unroll
    for (int kt = 0; kt < 8; ++kt) {
      float4 w0 = *(const float4*)(wp + kt * 32);
      float4 w1 = *(const float4*)(wp + kt * 32 + 4);
      bf16x8 b;
      b[0] = f2bf(w0.x); b[1] = f2bf(w0.y); b[2] = f2bf(w0.z); b[3] = f2bf(w0.w);
      b[4] = f2bf(w1.x); b[5] = f2bf(w1.y); b[6] = f2bf(w1.z); b[7] = f2bf(w1.w);
      Bf[kt] = b;
    }
  }
  const float bv = bias[gh * 256 + n0 + l16];

  // staging: thread loads float4 #tid of the tile (row = tid>>6, col4 = tid&63)
  const int sr = tid >> 6, sc = tid & 63;
  const float* sbase = x + (size_t)(row0 + sr) * 4096 + g * 1024 + hh * 256 + sc * 4;

  float4 sreg;
  auto gload = [&](int t) { sreg = *(const float4*)(sbase + (size_t)t * 16 * 4096); };
  auto swrite = [&](int buf) {
    ushort4 u;
    u.x = (u16)f2bf(sreg.x); u.y = (u16)f2bf(sreg.y);
    u.z = (u16)f2bf(sreg.z); u.w = (u16)f2bf(sreg.w);
    *(ushort4*)&As[buf][sr * 264 + sc * 4] = u;
  };

  gload(0); swrite(0);
  __syncthreads();

  for (int t = 0; t < 16; ++t) {
    if (t + 1 < 16) gload(t + 1);

    f32x4 acc = (f32x4){0.f, 0.f, 0.f, 0.f};
#pragma unroll
    for (int kt = 0; kt < 8; ++kt) {
      bf16x8 a = *(const bf16x8*)&As[t & 1][l16 * 264 + kt * 32 + quad * 8];
      acc = __builtin_amdgcn_mfma_f32_16x16x32_bf16(a, Bf[kt], acc, 0, 0, 0);
    }

    // epilogue (fire-and-forget stores, overlap with next staging)
#pragma unroll
    for (int rr = 0; rr < 4; ++rr) {
      int rowi = row0 + t * 16 + quad * 4 + rr;
      int sx = rowi & (S_LEN - 1);
      int bx = rowi >> 11;
      size_t idx = (size_t)sx * NCH + bx * 1024 + hh * 256 + n0 + l16;
      float v = acc[rr] + bv;
      if (g == 1)      gi16[idx] = f2h(v);
      else if (g == 2) gf16[idx] = f2h(v);
      else if (g == 0) {
        float tz = 1.f - 2.f * __builtin_amdgcn_rcpf(1.f + __expf(2.f * v));
        gz16[idx] = (u16)f2bf(tz);
      } else {
        float s = __builtin_amdgcn_rcpf(1.f + __expf(-v));
        go16[idx] = (u16)f2bf(s);
      }
    }

    if (t + 1 < 16) {
      swrite((t + 1) & 1);
      __syncthreads();
    }
  }
}

// ---------------------------------------------------------------------------
// Kernel 2: pass 1 — per (channel, 16-step chunk) locally-stabilized
// summaries: A = sum(f); B = stabilizer; D/Dn = c/n from zero state.
// 524288 threads (2x the old CHUNK=32 config: 32 waves/CU target).
// ---------------------------------------------------------------------------
__global__ __launch_bounds__(256) void scan_pass1(
    const u16* __restrict__ gz16, const u16* __restrict__ gi16,
    const u16* __restrict__ gf16, float* __restrict__ sums) {
  const int t  = blockIdx.x * 256 + threadIdx.x;   // 524288
  const int ch = t & (NCH - 1);
  const int ck = t >> 12;                           // 0..127
  const size_t base = (size_t)ck * CHUNK * NCH + ch;

  float A = 0.f, Bv = -1e30f, D = 0.f, Dn = 0.f;

  float z0[8], i0[8], f0[8], z1[8], i1[8], f1[8];
#pragma unroll
  for (int j = 0; j < 8; ++j) {
    size_t off = base + (size_t)j * NCH;
    z0[j] = bf2f(gz16[off]); i0[j] = h2f(gi16[off]); f0[j] = h2f(gf16[off]);
  }
#pragma unroll
  for (int j = 0; j < 8; ++j) {
    size_t off = base + (size_t)(8 + j) * NCH;
    z1[j] = bf2f(gz16[off]); i1[j] = h2f(gi16[off]); f1[j] = h2f(gf16[off]);
  }

  auto step = [&](float z, float i, float f) {
    float Bn = fmaxf(Bv + f, i);
    float e1 = __expf(Bv + f - Bn);
    float e2 = __expf(i - Bn);
    D  = e1 * D + e2 * z;
    Dn = e1 * Dn + e2;
    A += f;
    Bv = Bn;
  };

#pragma unroll
  for (int j = 0; j < 8; ++j) step(z0[j], i0[j], f0[j]);
#pragma unroll
  for (int j = 0; j < 8; ++j) step(z1[j], i1[j], f1[j]);

  const size_t idx = (size_t)ck * NCH + ch;
  sums[idx]          = A;
  sums[SN + idx]     = Bv;
  sums[2 * SN + idx] = D;
  sums[3 * SN + idx] = Dn;
}

// ---------------------------------------------------------------------------
// Kernel 3: pass 2 — wave-parallel scan over 128 chunks. One 64-lane wave
// per channel; lane l folds chunk pair (2l, 2l+1), Hillis-Steele inclusive
// scan of pair-summaries (6 shfl_up rounds), exclusive via shift; identity
// = (A=0, B=-1e30, D=0, N=0) keeps lane 0 uniform. Writes entering (c,n,m)
// for both chunks of the pair.
// ---------------------------------------------------------------------------
__global__ __launch_bounds__(256) void scan_pass2(
    const float* __restrict__ sums, float* __restrict__ ent) {
  const int gt   = blockIdx.x * 256 + threadIdx.x;   // 262144 threads
  const int ch   = gt >> 6;                          // 0..4095
  const int lane = gt & 63;                          // chunk pair index

  const size_t i0 = (size_t)(2 * lane) * NCH + ch;
  const size_t i1 = (size_t)(2 * lane + 1) * NCH + ch;
  float A0 = sums[i0], B0 = sums[SN + i0], D0 = sums[2 * SN + i0], N0 = sums[3 * SN + i0];
  float A1 = sums[i1], B1 = sums[SN + i1], D1 = sums[2 * SN + i1], N1 = sums[3 * SN + i1];

  // pair = combine(early=chunk 2l, late=chunk 2l+1)
  float A, B, D, N;
  {
    float Bn = fmaxf(B0 + A1, B1);
    D = __expf(B0 + A1 - Bn) * D0 + __expf(B1 - Bn) * D1;
    N = __expf(B0 + A1 - Bn) * N0 + __expf(B1 - Bn) * N1;
    A = A0 + A1;
    B = Bn;
  }

#pragma unroll
  for (int d = 1; d < 64; d <<= 1) {
    float Ae = __shfl_up(A, d, 64);
    float Be = __shfl_up(B, d, 64);
    float De = __shfl_up(D, d, 64);
    float Ne = __shfl_up(N, d, 64);
    if (lane >= d) {
      float Bn = fmaxf(Be + A, B);
      float e1 = __expf(Be + A - Bn);
      float e2 = __expf(B - Bn);
      D = e1 * De + e2 * D;
      N = e1 * Ne + e2 * N;
      A = A + Ae;
      B = Bn;
    }
  }

  // exclusive prefix E (transform of chunks 0..2l-1); identity for lane 0
  float Ae = __shfl_up(A, 1, 64);
  float Be = __shfl_up(B, 1, 64);
  float De = __shfl_up(D, 1, 64);
  float Ne = __shfl_up(N, 1, 64);
  if (lane == 0) { Ae = 0.f; Be = -1e30f; De = 0.f; Ne = 0.f; }

  // entering state for chunk 2l: apply E to (c,n,m)=(0,0,0)
  {
    float m = fmaxf(Ae, Be);
    float eb = __expf(Be - m);
    ent[i0]          = eb * De;
    ent[SN + i0]     = eb * Ne;
    ent[2 * SN + i0] = m;
  }
  // F = combine(E, chunk 2l); entering for chunk 2l+1 = apply F to zeros
  {
    float Bf_ = fmaxf(Be + A0, B0);
    float e1 = __expf(Be + A0 - Bf_);
    float e2 = __expf(B0 - Bf_);
    float Df_ = e1 * De + e2 * D0;
    float Nf_ = e1 * Ne + e2 * N0;
    float Af_ = Ae + A0;
    float m = fmaxf(Af_, Bf_);
    float eb = __expf(Bf_ - m);
    ent[i1]          = eb * Df_;
    ent[SN + i1]     = eb * Nf_;
    ent[2 * SN + i1] = m;
  }
}

// ---------------------------------------------------------------------------
// Kernel 4: pass 3 — read entering state, replay 16 steps of the original
// recurrence, write h. Last chunk writes finals. 524288 threads.
// ---------------------------------------------------------------------------
__global__ __launch_bounds__(256) void scan_pass3(
    const u16* __restrict__ gz16, const u16* __restrict__ gi16,
    const u16* __restrict__ gf16, const u16* __restrict__ go16,
    const float* __restrict__ ent, float* __restrict__ out) {
  const int t  = blockIdx.x * 256 + threadIdx.x;   // 524288
  const int ch = t & (NCH - 1);
  const int ck = t >> 12;                           // 0..127

  const size_t idx0 = (size_t)ck * NCH + ch;
  float c = ent[idx0];
  float n = ent[SN + idx0];
  float m = ent[2 * SN + idx0];

  const int b = ch >> 10, d = ch & 1023;
  const size_t base = (size_t)ck * CHUNK * NCH + ch;
  float* hout = out + (size_t)b * (S_LEN * 1024) + (size_t)(ck * CHUNK) * 1024 + d;

  float hv = 0.f;
  float z0[8], i0[8], f0[8], o0[8], z1[8], i1[8], f1[8], o1[8];
#pragma unroll
  for (int j = 0; j < 8; ++j) {
    size_t off = base + (size_t)j * NCH;
    z0[j] = bf2f(gz16[off]); i0[j] = h2f(gi16[off]);
    f0[j] = h2f(gf16[off]); o0[j] = bf2f(go16[off]);
  }
#pragma unroll
  for (int j = 0; j < 8; ++j) {
    size_t off = base + (size_t)(8 + j) * NCH;
    z1[j] = bf2f(gz16[off]); i1[j] = h2f(gi16[off]);
    f1[j] = h2f(gf16[off]); o1[j] = bf2f(go16[off]);
  }

  auto step = [&](float z, float i, float f, float o, int s) {
    float mn = fmaxf(f + m, i);
    float fh = __expf(f + m - mn);
    float ih = __expf(i - mn);
    c = fh * c + ih * z;
    n = fh * n + ih;
    m = mn;
    hv = o * c * __builtin_amdgcn_rcpf(n + EPS);
    hout[(size_t)s * 1024] = hv;
  };

#pragma unroll
  for (int j = 0; j < 8; ++j) step(z0[j], i0[j], f0[j], o0[j], j);
#pragma unroll
  for (int j = 0; j < 8; ++j) step(z1[j], i1[j], f1[j], o1[j], 8 + j);

  if (ck == NCHUNK - 1) {
    float* fin = out + (size_t)BATCH * S_LEN * 1024;   // 8,388,608
    fin[ch]            = hv;
    fin[NCH + ch]      = c;
    fin[2 * NCH + ch]  = n;
    fin[3 * NCH + ch]  = m;
  }
}

extern "C" void kernel_launch(void* const* d_in, const int* in_sizes, int n_in,
                              void* d_out, int out_size, void* d_ws, size_t ws_size,
                              hipStream_t stream) {
  const float* x    = (const float*)d_in[0];   // [4,2048,4096] fp32
  const float* W    = (const float*)d_in[1];   // [4,4,256,256] fp32
  const float* bias = (const float*)d_in[2];   // [4,4,256] fp32
  float* out = (float*)d_out;

  // ws layout: z bf16 | i fp16 | f fp16 | o bf16 | sums 4*SN | ent 3*SN
  u16*   gz16 = (u16*)d_ws;                       // 16.78 MB
  u16*   gi16 = gz16 + PLANE;                     // 16.78 MB
  u16*   gf16 = gi16 + PLANE;                     // 16.78 MB
  u16*   go16 = gf16 + PLANE;                     // 16.78 MB
  float* sums = (float*)(go16 + PLANE);           // 8.39 MB
  float* ent  = sums + 4 * SN;                    // 6.29 MB  (total ~82 MB)

  gates_gemm6<<<dim3(16, 32), dim3(1024), 0, stream>>>(x, W, bias, gz16, gi16, gf16, go16);
  scan_pass1<<<dim3(2048), dim3(256), 0, stream>>>(gz16, gi16, gf16, sums);
  scan_pass2<<<dim3(1024), dim3(256), 0, stream>>>(sums, ent);
  scan_pass3<<<dim3(2048), dim3(256), 0, stream>>>(gz16, gi16, gf16, go16, ent, out);
}

// Round 5
// 274.684 us; speedup vs baseline: 1.1223x; 1.0135x over previous
//
#include <hip/hip_runtime.h>
#include <cstdint>

#define S_LEN   2048
#define BATCH   4
#define NCH     4096                    // B*NH*HD channels
#define CHUNK   32
#define NCHUNK  64
#define PLANE   ((size_t)S_LEN * NCH)   // per-gate plane: 8,388,608 elems
#define SN      ((size_t)NCHUNK * NCH)  // 262144 summary slots
#define EPS     1e-8f

using bf16x8 = __attribute__((ext_vector_type(8))) short;
using u16x8  = __attribute__((ext_vector_type(8))) unsigned short;
using f32x4  = __attribute__((ext_vector_type(4))) float;
typedef unsigned short u16;

__device__ __forceinline__ short f2bf(float f) {
  uint32_t u = __builtin_bit_cast(uint32_t, f);
  u += 0x7fffu + ((u >> 16) & 1u);
  return (short)(u >> 16);
}
__device__ __forceinline__ float bf2f(u16 u) {
  return __builtin_bit_cast(float, (uint32_t)u << 16);
}
__device__ __forceinline__ u16 f2h(float f) {
  _Float16 h = (_Float16)f;
  return __builtin_bit_cast(unsigned short, h);
}
__device__ __forceinline__ float h2f(u16 u) {
  return (float)__builtin_bit_cast(_Float16, u);
}

// Gate planes are stored CHUNK-MAJOR: plane[ck][ch][s_in_chunk], i.e.
// idx = (ck*NCH + ch)*CHUNK + (s&31). Scan threads then read 64B contiguous
// per gate (4x 16B vector loads); a wave covers a contiguous 4KB region.

// ---------------------------------------------------------------------------
// Kernel 1: gate projection — round-3 proven structure (87.9 us). Changes:
// chunk-major store layout; the 4 rr outputs (4 contiguous s in one chunk)
// are packed into ONE ushort4 (8B) store per lane per tile.
// ---------------------------------------------------------------------------
__global__ __launch_bounds__(1024) void gates_gemm7(
    const float* __restrict__ x, const float* __restrict__ W,
    const float* __restrict__ bias,
    u16* __restrict__ gz16, u16* __restrict__ gi16, u16* __restrict__ gf16,
    u16* __restrict__ go16) {
  __shared__ u16 As[2][16 * 264];   // 2 x 8448 B

  const int gh  = blockIdx.x;          // g*4+h
  const int rg  = blockIdx.y;          // 0..31, 256 rows each
  const int g   = gh >> 2, hh = gh & 3;
  const int tid = threadIdx.x;
  const int wave = tid >> 6, lane = tid & 63;
  const int l16 = lane & 15, quad = lane >> 4;
  const int n0  = wave * 16;
  const int row0 = rg * 256;

  // B fragments for this wave's 16-col strip (held all kernel)
  bf16x8 Bf[8];
  {
    const float* wp = W + ((size_t)gh << 16) + (n0 + l16) * 256 + quad * 8;
#pragma unroll
    for (int kt = 0; kt < 8; ++kt) {
      float4 w0 = *(const float4*)(wp + kt * 32);
      float4 w1 = *(const float4*)(wp + kt * 32 + 4);
      bf16x8 b;
      b[0] = f2bf(w0.x); b[1] = f2bf(w0.y); b[2] = f2bf(w0.z); b[3] = f2bf(w0.w);
      b[4] = f2bf(w1.x); b[5] = f2bf(w1.y); b[6] = f2bf(w1.z); b[7] = f2bf(w1.w);
      Bf[kt] = b;
    }
  }
  const float bv = bias[gh * 256 + n0 + l16];

  // staging: thread loads float4 #tid of the tile (row = tid>>6, col4 = tid&63)
  const int sr = tid >> 6, sc = tid & 63;
  const float* sbase = x + (size_t)(row0 + sr) * 4096 + g * 1024 + hh * 256 + sc * 4;

  float4 sreg;
  auto gload = [&](int t) { sreg = *(const float4*)(sbase + (size_t)t * 16 * 4096); };
  auto swrite = [&](int buf) {
    ushort4 u;
    u.x = (u16)f2bf(sreg.x); u.y = (u16)f2bf(sreg.y);
    u.z = (u16)f2bf(sreg.z); u.w = (u16)f2bf(sreg.w);
    *(ushort4*)&As[buf][sr * 264 + sc * 4] = u;
  };

  gload(0); swrite(0);
  __syncthreads();

  for (int t = 0; t < 16; ++t) {
    if (t + 1 < 16) gload(t + 1);

    f32x4 acc = (f32x4){0.f, 0.f, 0.f, 0.f};
#pragma unroll
    for (int kt = 0; kt < 8; ++kt) {
      bf16x8 a = *(const bf16x8*)&As[t & 1][l16 * 264 + kt * 32 + quad * 8];
      acc = __builtin_amdgcn_mfma_f32_16x16x32_bf16(a, Bf[kt], acc, 0, 0, 0);
    }

    // epilogue: 4 contiguous s (same chunk) -> one ushort4 store
    {
      int rowb = row0 + t * 16 + quad * 4;        // aligned to 4, no chunk cross
      int sx   = rowb & (S_LEN - 1);
      int bx   = rowb >> 11;
      int ck   = sx >> 5, sin = sx & 31;          // sin ≡ 0 (mod 4)
      int ch   = bx * 1024 + hh * 256 + n0 + l16;
      size_t idx = ((size_t)ck * NCH + ch) * CHUNK + sin;

      float v0 = acc[0] + bv, v1 = acc[1] + bv, v2 = acc[2] + bv, v3 = acc[3] + bv;
      ushort4 uo;
      if (g == 1) {
        uo.x = f2h(v0); uo.y = f2h(v1); uo.z = f2h(v2); uo.w = f2h(v3);
        *(ushort4*)&gi16[idx] = uo;
      } else if (g == 2) {
        uo.x = f2h(v0); uo.y = f2h(v1); uo.z = f2h(v2); uo.w = f2h(v3);
        *(ushort4*)&gf16[idx] = uo;
      } else if (g == 0) {
        auto tz = [](float v) {
          return (u16)f2bf(1.f - 2.f * __builtin_amdgcn_rcpf(1.f + __expf(2.f * v)));
        };
        uo.x = tz(v0); uo.y = tz(v1); uo.z = tz(v2); uo.w = tz(v3);
        *(ushort4*)&gz16[idx] = uo;
      } else {
        auto sg = [](float v) {
          return (u16)f2bf(__builtin_amdgcn_rcpf(1.f + __expf(-v)));
        };
        uo.x = sg(v0); uo.y = sg(v1); uo.z = sg(v2); uo.w = sg(v3);
        *(ushort4*)&go16[idx] = uo;
      }
    }

    if (t + 1 < 16) {
      swrite((t + 1) & 1);
      __syncthreads();
    }
  }
}

// ---------------------------------------------------------------------------
// Kernel 2: pass 1 — per (channel, 32-step chunk) summaries. Chunk-major
// reads: each gate = 4x 16B contiguous vector loads (64B/thread).
// ---------------------------------------------------------------------------
__global__ __launch_bounds__(256) void scan_pass1(
    const u16* __restrict__ gz16, const u16* __restrict__ gi16,
    const u16* __restrict__ gf16, float* __restrict__ sums) {
  const int t  = blockIdx.x * 256 + threadIdx.x;   // 262144
  const int ch = t & (NCH - 1);
  const int ck = t >> 12;                           // 0..63
  const size_t cb = ((size_t)ck * NCH + ch) * CHUNK;

  u16x8 zv[4], iv[4], fv[4];
#pragma unroll
  for (int q = 0; q < 4; ++q) zv[q] = *(const u16x8*)(gz16 + cb + q * 8);
#pragma unroll
  for (int q = 0; q < 4; ++q) iv[q] = *(const u16x8*)(gi16 + cb + q * 8);
#pragma unroll
  for (int q = 0; q < 4; ++q) fv[q] = *(const u16x8*)(gf16 + cb + q * 8);

  float A = 0.f, Bv = -1e30f, D = 0.f, Dn = 0.f;

  auto step = [&](float z, float i, float f) {
    float Bn = fmaxf(Bv + f, i);
    float e1 = __expf(Bv + f - Bn);
    float e2 = __expf(i - Bn);
    D  = e1 * D + e2 * z;
    Dn = e1 * Dn + e2;
    A += f;
    Bv = Bn;
  };

#pragma unroll
  for (int q = 0; q < 4; ++q)
#pragma unroll
    for (int j = 0; j < 8; ++j)
      step(bf2f(zv[q][j]), h2f(iv[q][j]), h2f(fv[q][j]));

  const size_t idx = (size_t)ck * NCH + ch;
  sums[idx]          = A;
  sums[SN + idx]     = Bv;
  sums[2 * SN + idx] = D;
  sums[3 * SN + idx] = Dn;
}

// ---------------------------------------------------------------------------
// Kernel 3: pass 2 — wave-parallel scan (round-2 proven). One wave per
// channel, lane = chunk; Hillis-Steele inclusive scan, exclusive via shift.
// ---------------------------------------------------------------------------
__global__ __launch_bounds__(256) void scan_pass2(
    const float* __restrict__ sums, float* __restrict__ ent) {
  const int gt   = blockIdx.x * 256 + threadIdx.x;   // 262144 threads
  const int ch   = gt >> 6;                          // 0..4095
  const int lane = gt & 63;                          // chunk index

  const size_t idx = (size_t)lane * NCH + ch;
  float A = sums[idx];
  float B = sums[SN + idx];
  float D = sums[2 * SN + idx];
  float N = sums[3 * SN + idx];

#pragma unroll
  for (int d = 1; d < 64; d <<= 1) {
    float A1 = __shfl_up(A, d, 64);
    float B1 = __shfl_up(B, d, 64);
    float D1 = __shfl_up(D, d, 64);
    float N1 = __shfl_up(N, d, 64);
    if (lane >= d) {
      float Bn = fmaxf(B1 + A, B);
      float e1 = __expf(B1 + A - Bn);
      float e2 = __expf(B - Bn);
      D = e1 * D1 + e2 * D;
      N = e1 * N1 + e2 * N;
      A = A + A1;
      B = Bn;
    }
  }

  // exclusive prefix = inclusive of lane-1; lane 0 = identity
  float Ae = __shfl_up(A, 1, 64);
  float Be = __shfl_up(B, 1, 64);
  float De = __shfl_up(D, 1, 64);
  float Ne = __shfl_up(N, 1, 64);

  float c, n, m;
  if (lane == 0) {
    c = 0.f; n = 0.f; m = 0.f;
  } else {
    m = fmaxf(Ae, Be);           // transform applied to (c,n,m)=(0,0,0)
    float eb = __expf(Be - m);
    c = eb * De;
    n = eb * Ne;
  }

  ent[idx]          = c;
  ent[SN + idx]     = n;
  ent[2 * SN + idx] = m;
}

// ---------------------------------------------------------------------------
// Kernel 4: pass 3 — read entering state, replay 32 steps, write h.
// Chunk-major gate reads (4x 16B per gate). h writes in required layout.
// ---------------------------------------------------------------------------
__global__ __launch_bounds__(256) void scan_pass3(
    const u16* __restrict__ gz16, const u16* __restrict__ gi16,
    const u16* __restrict__ gf16, const u16* __restrict__ go16,
    const float* __restrict__ ent, float* __restrict__ out) {
  const int t  = blockIdx.x * 256 + threadIdx.x;   // 262144
  const int ch = t & (NCH - 1);
  const int ck = t >> 12;                           // 0..63
  const size_t cb = ((size_t)ck * NCH + ch) * CHUNK;

  u16x8 zv[4], iv[4], fv[4], ov[4];
#pragma unroll
  for (int q = 0; q < 4; ++q) zv[q] = *(const u16x8*)(gz16 + cb + q * 8);
#pragma unroll
  for (int q = 0; q < 4; ++q) iv[q] = *(const u16x8*)(gi16 + cb + q * 8);
#pragma unroll
  for (int q = 0; q < 4; ++q) fv[q] = *(const u16x8*)(gf16 + cb + q * 8);
#pragma unroll
  for (int q = 0; q < 4; ++q) ov[q] = *(const u16x8*)(go16 + cb + q * 8);

  const size_t idx0 = (size_t)ck * NCH + ch;
  float c = ent[idx0];
  float n = ent[SN + idx0];
  float m = ent[2 * SN + idx0];

  const int b = ch >> 10, d = ch & 1023;
  float* hout = out + (size_t)b * (S_LEN * 1024) + (size_t)(ck * CHUNK) * 1024 + d;

  float hv = 0.f;
#pragma unroll
  for (int q = 0; q < 4; ++q) {
#pragma unroll
    for (int j = 0; j < 8; ++j) {
      float z = bf2f(zv[q][j]);
      float i = h2f(iv[q][j]);
      float f = h2f(fv[q][j]);
      float o = bf2f(ov[q][j]);
      float mn = fmaxf(f + m, i);
      float fh = __expf(f + m - mn);
      float ih = __expf(i - mn);
      c = fh * c + ih * z;
      n = fh * n + ih;
      m = mn;
      hv = o * c * __builtin_amdgcn_rcpf(n + EPS);
      hout[(size_t)(q * 8 + j) * 1024] = hv;
    }
  }

  if (ck == NCHUNK - 1) {
    float* fin = out + (size_t)BATCH * S_LEN * 1024;   // 8,388,608
    fin[ch]            = hv;
    fin[NCH + ch]      = c;
    fin[2 * NCH + ch]  = n;
    fin[3 * NCH + ch]  = m;
  }
}

extern "C" void kernel_launch(void* const* d_in, const int* in_sizes, int n_in,
                              void* d_out, int out_size, void* d_ws, size_t ws_size,
                              hipStream_t stream) {
  const float* x    = (const float*)d_in[0];   // [4,2048,4096] fp32
  const float* W    = (const float*)d_in[1];   // [4,4,256,256] fp32
  const float* bias = (const float*)d_in[2];   // [4,4,256] fp32
  float* out = (float*)d_out;

  // ws layout: z bf16 | i fp16 | f fp16 | o bf16 (all chunk-major) | sums | ent
  u16*   gz16 = (u16*)d_ws;                       // 16.78 MB
  u16*   gi16 = gz16 + PLANE;                     // 16.78 MB
  u16*   gf16 = gi16 + PLANE;                     // 16.78 MB
  u16*   go16 = gf16 + PLANE;                     // 16.78 MB
  float* sums = (float*)(go16 + PLANE);           // 4.19 MB
  float* ent  = sums + 4 * SN;                    // 3.15 MB  (total ~74 MB)

  gates_gemm7<<<dim3(16, 32), dim3(1024), 0, stream>>>(x, W, bias, gz16, gi16, gf16, go16);
  scan_pass1<<<dim3(1024), dim3(256), 0, stream>>>(gz16, gi16, gf16, sums);
  scan_pass2<<<dim3(1024), dim3(256), 0, stream>>>(sums, ent);
  scan_pass3<<<dim3(1024), dim3(256), 0, stream>>>(gz16, gi16, gf16, go16, ent, out);
}

// Round 6
// 250.120 us; speedup vs baseline: 1.2325x; 1.0982x over previous
//
#include <hip/hip_runtime.h>
#include <cstdint>

#define S_LEN   2048
#define BATCH   4
#define NCH     4096                    // B*NH*HD channels
#define CHUNK   32
#define NCHUNK  64
#define PLANE   ((size_t)S_LEN * NCH)   // per-gate plane: 8,388,608 elems
#define EPS     1e-8f

using bf16x8 = __attribute__((ext_vector_type(8))) short;
using u16x8  = __attribute__((ext_vector_type(8))) unsigned short;
using f32x4  = __attribute__((ext_vector_type(4))) float;
typedef unsigned short u16;

__device__ __forceinline__ short f2bf(float f) {
  uint32_t u = __builtin_bit_cast(uint32_t, f);
  u += 0x7fffu + ((u >> 16) & 1u);
  return (short)(u >> 16);
}
__device__ __forceinline__ float bf2f(u16 u) {
  return __builtin_bit_cast(float, (uint32_t)u << 16);
}
__device__ __forceinline__ u16 f2h(float f) {
  _Float16 h = (_Float16)f;
  return __builtin_bit_cast(unsigned short, h);
}
__device__ __forceinline__ float h2f(u16 u) {
  return (float)__builtin_bit_cast(_Float16, u);
}

// Gate planes are stored CHUNK-MAJOR: plane[ck][ch][s_in_chunk], i.e.
// idx = (ck*NCH + ch)*CHUNK + (s&31).

// ---------------------------------------------------------------------------
// Kernel 1: gate projection — UNCHANGED from round 5 (90 us measured).
// ---------------------------------------------------------------------------
__global__ __launch_bounds__(1024) void gates_gemm7(
    const float* __restrict__ x, const float* __restrict__ W,
    const float* __restrict__ bias,
    u16* __restrict__ gz16, u16* __restrict__ gi16, u16* __restrict__ gf16,
    u16* __restrict__ go16) {
  __shared__ u16 As[2][16 * 264];   // 2 x 8448 B

  const int gh  = blockIdx.x;          // g*4+h
  const int rg  = blockIdx.y;          // 0..31, 256 rows each
  const int g   = gh >> 2, hh = gh & 3;
  const int tid = threadIdx.x;
  const int wave = tid >> 6, lane = tid & 63;
  const int l16 = lane & 15, quad = lane >> 4;
  const int n0  = wave * 16;
  const int row0 = rg * 256;

  // B fragments for this wave's 16-col strip (held all kernel)
  bf16x8 Bf[8];
  {
    const float* wp = W + ((size_t)gh << 16) + (n0 + l16) * 256 + quad * 8;
#pragma unroll
    for (int kt = 0; kt < 8; ++kt) {
      float4 w0 = *(const float4*)(wp + kt * 32);
      float4 w1 = *(const float4*)(wp + kt * 32 + 4);
      bf16x8 b;
      b[0] = f2bf(w0.x); b[1] = f2bf(w0.y); b[2] = f2bf(w0.z); b[3] = f2bf(w0.w);
      b[4] = f2bf(w1.x); b[5] = f2bf(w1.y); b[6] = f2bf(w1.z); b[7] = f2bf(w1.w);
      Bf[kt] = b;
    }
  }
  const float bv = bias[gh * 256 + n0 + l16];

  // staging: thread loads float4 #tid of the tile (row = tid>>6, col4 = tid&63)
  const int sr = tid >> 6, sc = tid & 63;
  const float* sbase = x + (size_t)(row0 + sr) * 4096 + g * 1024 + hh * 256 + sc * 4;

  float4 sreg;
  auto gload = [&](int t) { sreg = *(const float4*)(sbase + (size_t)t * 16 * 4096); };
  auto swrite = [&](int buf) {
    ushort4 u;
    u.x = (u16)f2bf(sreg.x); u.y = (u16)f2bf(sreg.y);
    u.z = (u16)f2bf(sreg.z); u.w = (u16)f2bf(sreg.w);
    *(ushort4*)&As[buf][sr * 264 + sc * 4] = u;
  };

  gload(0); swrite(0);
  __syncthreads();

  for (int t = 0; t < 16; ++t) {
    if (t + 1 < 16) gload(t + 1);

    f32x4 acc = (f32x4){0.f, 0.f, 0.f, 0.f};
#pragma unroll
    for (int kt = 0; kt < 8; ++kt) {
      bf16x8 a = *(const bf16x8*)&As[t & 1][l16 * 264 + kt * 32 + quad * 8];
      acc = __builtin_amdgcn_mfma_f32_16x16x32_bf16(a, Bf[kt], acc, 0, 0, 0);
    }

    // epilogue: 4 contiguous s (same chunk) -> one ushort4 store
    {
      int rowb = row0 + t * 16 + quad * 4;        // aligned to 4, no chunk cross
      int sx   = rowb & (S_LEN - 1);
      int bx   = rowb >> 11;
      int ck   = sx >> 5, sin = sx & 31;          // sin ≡ 0 (mod 4)
      int ch   = bx * 1024 + hh * 256 + n0 + l16;
      size_t idx = ((size_t)ck * NCH + ch) * CHUNK + sin;

      float v0 = acc[0] + bv, v1 = acc[1] + bv, v2 = acc[2] + bv, v3 = acc[3] + bv;
      ushort4 uo;
      if (g == 1) {
        uo.x = f2h(v0); uo.y = f2h(v1); uo.z = f2h(v2); uo.w = f2h(v3);
        *(ushort4*)&gi16[idx] = uo;
      } else if (g == 2) {
        uo.x = f2h(v0); uo.y = f2h(v1); uo.z = f2h(v2); uo.w = f2h(v3);
        *(ushort4*)&gf16[idx] = uo;
      } else if (g == 0) {
        auto tz = [](float v) {
          return (u16)f2bf(1.f - 2.f * __builtin_amdgcn_rcpf(1.f + __expf(2.f * v)));
        };
        uo.x = tz(v0); uo.y = tz(v1); uo.z = tz(v2); uo.w = tz(v3);
        *(ushort4*)&gz16[idx] = uo;
      } else {
        auto sg = [](float v) {
          return (u16)f2bf(__builtin_amdgcn_rcpf(1.f + __expf(-v)));
        };
        uo.x = sg(v0); uo.y = sg(v1); uo.z = sg(v2); uo.w = sg(v3);
        *(ushort4*)&go16[idx] = uo;
      }
    }

    if (t + 1 < 16) {
      swrite((t + 1) & 1);
      __syncthreads();
    }
  }
}

// ---------------------------------------------------------------------------
// Kernel 2: FUSED scan — replaces pass1+pass2+pass3 with ONE kernel using
// only block-local synchronization. Block = 1024 thr = 16 channels x 64
// chunk-slots; grid = 256 blocks (1/CU, 16 waves/CU).
//   Phase A (thread = (ch_local, slot=chunk)): 32-step chunk summary
//     (A,B,D,N) -> LDS [slot][ch]. z,i,f stay in REGISTERS for Phase C.
//   Phase B (wave w = channel w, lane = slot): proven Hillis-Steele wave
//     scan of the 64 chunk transforms; exclusive prefix -> entering (c,n,m)
//     -> LDS (columns are wave-private; no sync inside B).
//   Phase C (back to (ch_local, slot)): replay 32 steps, write h; slot 63
//     writes finals.
// Eliminates: 2 kernel launches, sums/ent global round-trips (14 MB), and
// the second read of z,i,f (50 MB).
// ---------------------------------------------------------------------------
__global__ __launch_bounds__(1024) void scan_fused(
    const u16* __restrict__ gz16, const u16* __restrict__ gi16,
    const u16* __restrict__ gf16, const u16* __restrict__ go16,
    float* __restrict__ out) {
  __shared__ float sA[64][17], sB[64][17], sD[64][17], sN[64][17];  // 17.4 KB

  const int tid = threadIdx.x;
  const int ch_local = tid & 15;
  const int slot     = tid >> 4;            // chunk index 0..63
  const int ch       = blockIdx.x * 16 + ch_local;
  const size_t cb    = ((size_t)slot * NCH + ch) * CHUNK;

  // ---------------- Phase A: chunk summary (z,i,f kept in regs) ----------
  u16x8 zv[4], iv[4], fv[4];
#pragma unroll
  for (int q = 0; q < 4; ++q) zv[q] = *(const u16x8*)(gz16 + cb + q * 8);
#pragma unroll
  for (int q = 0; q < 4; ++q) iv[q] = *(const u16x8*)(gi16 + cb + q * 8);
#pragma unroll
  for (int q = 0; q < 4; ++q) fv[q] = *(const u16x8*)(gf16 + cb + q * 8);

  {
    float A = 0.f, Bv = -1e30f, D = 0.f, Dn = 0.f;
#pragma unroll
    for (int q = 0; q < 4; ++q) {
#pragma unroll
      for (int j = 0; j < 8; ++j) {
        float z = bf2f(zv[q][j]);
        float i = h2f(iv[q][j]);
        float f = h2f(fv[q][j]);
        float Bn = fmaxf(Bv + f, i);
        float e1 = __expf(Bv + f - Bn);
        float e2 = __expf(i - Bn);
        D  = e1 * D + e2 * z;
        Dn = e1 * Dn + e2;
        A += f;
        Bv = Bn;
      }
    }
    sA[slot][ch_local] = A;
    sB[slot][ch_local] = Bv;
    sD[slot][ch_local] = D;
    sN[slot][ch_local] = Dn;
  }
  __syncthreads();

  // ---------------- Phase B: wave scan (wave = channel, lane = chunk) ----
  {
    const int w    = tid >> 6;    // 0..15: channel column
    const int lane = tid & 63;    // chunk index

    float A = sA[lane][w];
    float B = sB[lane][w];
    float D = sD[lane][w];
    float N = sN[lane][w];

#pragma unroll
    for (int d = 1; d < 64; d <<= 1) {
      float A1 = __shfl_up(A, d, 64);
      float B1 = __shfl_up(B, d, 64);
      float D1 = __shfl_up(D, d, 64);
      float N1 = __shfl_up(N, d, 64);
      if (lane >= d) {
        float Bn = fmaxf(B1 + A, B);
        float e1 = __expf(B1 + A - Bn);
        float e2 = __expf(B - Bn);
        D = e1 * D1 + e2 * D;
        N = e1 * N1 + e2 * N;
        A = A + A1;
        B = Bn;
      }
    }

    // exclusive prefix = inclusive of lane-1; lane 0 = identity
    float Ae = __shfl_up(A, 1, 64);
    float Be = __shfl_up(B, 1, 64);
    float De = __shfl_up(D, 1, 64);
    float Ne = __shfl_up(N, 1, 64);

    float c, n, m;
    if (lane == 0) {
      c = 0.f; n = 0.f; m = 0.f;
    } else {
      m = fmaxf(Ae, Be);           // transform applied to (c,n,m)=(0,0,0)
      float eb = __expf(Be - m);
      c = eb * De;
      n = eb * Ne;
    }

    // columns are wave-private: safe to overwrite without an extra sync
    sA[lane][w] = c;
    sB[lane][w] = n;
    sD[lane][w] = m;
  }
  __syncthreads();

  // ---------------- Phase C: replay 32 steps, write h --------------------
  {
    float c = sA[slot][ch_local];
    float n = sB[slot][ch_local];
    float m = sD[slot][ch_local];

    u16x8 ov[4];
#pragma unroll
    for (int q = 0; q < 4; ++q) ov[q] = *(const u16x8*)(go16 + cb + q * 8);

    const int b = ch >> 10, d = ch & 1023;
    float* hout = out + (size_t)b * (S_LEN * 1024) + (size_t)(slot * CHUNK) * 1024 + d;

    float hv = 0.f;
#pragma unroll
    for (int q = 0; q < 4; ++q) {
#pragma unroll
      for (int j = 0; j < 8; ++j) {
        float z = bf2f(zv[q][j]);
        float i = h2f(iv[q][j]);
        float f = h2f(fv[q][j]);
        float o = bf2f(ov[q][j]);
        float mn = fmaxf(f + m, i);
        float fh = __expf(f + m - mn);
        float ih = __expf(i - mn);
        c = fh * c + ih * z;
        n = fh * n + ih;
        m = mn;
        hv = o * c * __builtin_amdgcn_rcpf(n + EPS);
        hout[(size_t)(q * 8 + j) * 1024] = hv;
      }
    }

    if (slot == NCHUNK - 1) {
      float* fin = out + (size_t)BATCH * S_LEN * 1024;   // 8,388,608
      fin[ch]            = hv;
      fin[NCH + ch]      = c;
      fin[2 * NCH + ch]  = n;
      fin[3 * NCH + ch]  = m;
    }
  }
}

extern "C" void kernel_launch(void* const* d_in, const int* in_sizes, int n_in,
                              void* d_out, int out_size, void* d_ws, size_t ws_size,
                              hipStream_t stream) {
  const float* x    = (const float*)d_in[0];   // [4,2048,4096] fp32
  const float* W    = (const float*)d_in[1];   // [4,4,256,256] fp32
  const float* bias = (const float*)d_in[2];   // [4,4,256] fp32
  float* out = (float*)d_out;

  // ws layout: z bf16 | i fp16 | f fp16 | o bf16 (all chunk-major)
  u16*   gz16 = (u16*)d_ws;                       // 16.78 MB
  u16*   gi16 = gz16 + PLANE;                     // 16.78 MB
  u16*   gf16 = gi16 + PLANE;                     // 16.78 MB
  u16*   go16 = gf16 + PLANE;                     // 16.78 MB (total ~67 MB)

  gates_gemm7<<<dim3(16, 32), dim3(1024), 0, stream>>>(x, W, bias, gz16, gi16, gf16, go16);
  scan_fused<<<dim3(256), dim3(1024), 0, stream>>>(gz16, gi16, gf16, go16, out);
}